// Round 16
// baseline (398.194 us; speedup 1.0000x reference)
//
#include <hip/hip_runtime.h>
#include <stdint.h>

#define C_ 128

typedef __attribute__((ext_vector_type(8))) short short8;
typedef __attribute__((ext_vector_type(4))) float f32x4;
typedef __attribute__((ext_vector_type(4))) unsigned int u32x4;

__device__ __forceinline__ unsigned short f2bf(float x){
  unsigned u = __builtin_bit_cast(unsigned, x);
  return (unsigned short)((u + 0x7FFFu + ((u >> 16) & 1u)) >> 16);
}
__device__ __forceinline__ float bf2f(unsigned short h){
  unsigned u = ((unsigned)h) << 16;
  return __builtin_bit_cast(float, u);
}
__device__ __forceinline__ unsigned cvtpk(float lo, float hi){
  unsigned r;
  asm("v_cvt_pk_bf16_f32 %0, %1, %2" : "=v"(r) : "v"(lo), "v"(hi));
  return r;
}
__device__ __forceinline__ void bar(){
  asm volatile("s_waitcnt lgkmcnt(0)" ::: "memory");
  __builtin_amdgcn_s_barrier();
  asm volatile("" ::: "memory");
}

// mask dtype probe: lengths >= L/2 >= 4, so first 4 mask elems are true.
__device__ __forceinline__ bool mask_is_i32(const void* mask){
  return ((const unsigned*)mask)[0] == 1u;
}

// ---------------- fused scan + path-score: 16 samples / 512-thread block, 32 blocks --
// Scan structure = r15 (green, 350us): 8-wave j-split, distance-3 logits prefetch with
// off-chain p-precompute, 4 independent MFMA accumulators, eager renorm every 8 steps
// (lazy renorm blacklisted at 8 waves: r10/r11 NaN). NEW: crf_sent fused into the
// prologue (32 lanes per sample, shuffle-reduced into sent_lds) — kills the separate
// 15us kernel + launch gap.
__global__ __launch_bounds__(512, 1) void crf_scan(
    const float* __restrict__ logits,
    const float* __restrict__ trans,
    const int*   __restrict__ labels,
    const void*  __restrict__ mask,
    float* __restrict__ out,
    int L,
    const int* __restrict__ startp, const int* __restrict__ endp)
{
  __shared__ unsigned st[2 * 1024];   // 8 KB state, double-buffered, chunk-swizzled
  __shared__ float mred[16][8];
  __shared__ float sent_lds[16];

  const int tid = threadIdx.x;
  const int w   = tid >> 6;     // wave 0..7: owns tags [16w,16w+16)
  const int l   = tid & 63;
  const int lj  = l & 15;       // sample within block
  const int lg  = l >> 4;       // 0..3
  const int j0  = 16 * w + 4 * lg;
  const int n0  = blockIdx.x * 16;
  const int start_tag = *startp;
  const int end_tag   = *endp;
  const bool i32m = mask_is_i32(mask);
  const float LN2 = 0.69314718055994530942f;

  // ---- length of sample lj (each wave redundantly) ----
  int cnt = 0;
  {
    const int seg = L >> 2;
    if (i32m) {
      const int4* m4 = (const int4*)((const int*)mask + (size_t)(n0 + lj) * L + lg * seg);
      for (int i = 0; i < (seg >> 2); i++) {
        int4 v = m4[i];
        cnt += (v.x != 0) + (v.y != 0) + (v.z != 0) + (v.w != 0);
      }
    } else {
      const unsigned* mr = (const unsigned*)((const unsigned char*)mask + (size_t)(n0 + lj) * L + lg * seg);
      for (int i = 0; i < (seg >> 2); i++) cnt += __popc(mr[i]);
    }
    cnt += __shfl_xor(cnt, 16);
    cnt += __shfl_xor(cnt, 32);
  }
  const int len_n = cnt;
  int mn = len_n;
  mn = min(mn, __shfl_xor(mn, 1));
  mn = min(mn, __shfl_xor(mn, 2));
  mn = min(mn, __shfl_xor(mn, 4));
  mn = min(mn, __shfl_xor(mn, 8));
  const int T_main = (mn - 3) & ~3;   // multiple of 4; main loop fully alive

  // ---- fused path score: 32 lanes per sample; sum emis+trans over masked steps ----
  {
    const int s = tid >> 5;        // sample 0..15
    const int g = tid & 31;        // lane within sample-group
    const int*  lab  = labels + (size_t)(n0 + s) * L;
    const float* lrow = logits + (size_t)(n0 + s) * L * C_;
    const int*           m32 = (const int*)mask + (size_t)(n0 + s) * L;
    const unsigned char* m8  = (const unsigned char*)mask + (size_t)(n0 + s) * L;
    float acc = 0.f;
    for (int t = g; t < L; t += 32) {
      int mt = i32m ? m32[t] : (int)m8[t];
      if (mt) {
        int lt  = lab[t];
        int mnx = (t + 1 < L) ? (i32m ? m32[t + 1] : (int)m8[t + 1]) : 0;
        int nxt = mnx ? lab[t + 1] : end_tag;
        acc += lrow[(size_t)t * C_ + lt] + trans[(size_t)nxt * C_ + lt];
      }
    }
    #pragma unroll
    for (int m = 1; m < 32; m <<= 1) acc += __shfl_xor(acc, m);
    if (g == 0) sent_lds[s] = acc + trans[(size_t)lab[0] * C_ + start_tag];
  }

  // ---- A-frags: E^T rows [16w,16w+16), natural k-map k=32ks+8lg+e ----
  short8 af[4];
  #pragma unroll
  for (int ks = 0; ks < 4; ks++) {
    const float* tp = trans + (size_t)(16 * w + lj) * C_ + 32 * ks + 8 * lg;
    f32x4 e0 = *(const f32x4*)tp;
    f32x4 e1 = *(const f32x4*)(tp + 4);
    short8 f;
    #pragma unroll
    for (int i = 0; i < 4; i++) f[i] = (short)f2bf(expf(e0[i]));
    #pragma unroll
    for (int i = 0; i < 4; i++) f[4 + i] = (short)f2bf(expf(e1[i]));
    af[ks] = f;
  }

  // ---- init state: zeros + 1.0 at start_tag, in st[0] ----
  ((u32x4*)st)[tid] = (u32x4){0, 0, 0, 0};
  bar();
  if (tid < 16) {
    int phys = ((start_tag >> 3) ^ tid) & 15;
    st[tid * 64 + phys * 4 + ((start_tag & 7) >> 1)] =
        (start_tag & 1) ? 0x3F800000u : 0x00003F80u;
  }
  bar();

  unsigned prev0 = 0, prev1 = 0;
  #pragma unroll
  for (int i = 0; i < 4; i++)
    if (j0 + i == start_tag) {
      if (i == 0) prev0 |= 0x3F80u;
      if (i == 1) prev0 |= 0x3F80u << 16;
      if (i == 2) prev1 |= 0x3F80u;
      if (i == 3) prev1 |= 0x3F80u << 16;
    }

  // ---- LDS word offsets (u32 units), 16B-chunk XOR swizzle: phys = logical ^ lj ----
  const int wr_off = lj * 64 + ((((2 * w + (lg >> 1)) ^ lj) & 15) << 2) + ((lg & 1) << 1);
  const int rd0 = lj * 64 + ((((0 + lg) ^ lj) & 15) << 2);
  const int rd1 = lj * 64 + ((((4 + lg) ^ lj) & 15) << 2);
  const int rd2 = lj * 64 + ((((8 + lg) ^ lj) & 15) << 2);
  const int rd3 = lj * 64 + ((((12 + lg) ^ lj) & 15) << 2);

  const float L2E = 1.44269504088896340736f;
  const float NC  = -8.0f * L2E;

  // ---- logits: lane loads its own 4 tags; 4 rotating buffers (distance-3) ----
  const float* lbase = logits + (size_t)(n0 + lj) * L * C_ + j0;
  f32x4 lv0, lv1, lv2, lv3;
  asm volatile("global_load_dwordx4 %0, %1, off" : "=v"(lv0) : "v"(lbase));
  asm volatile("global_load_dwordx4 %0, %1, off" : "=v"(lv1) : "v"(lbase + C_));
  asm volatile("global_load_dwordx4 %0, %1, off" : "=v"(lv2) : "v"(lbase + 2 * C_));

  // prologue: p for step 0 (vmcnt(2): lv0 arrived, lv1/lv2 still in flight)
  float pc0, pc1, pc2, pc3;
  asm volatile("s_waitcnt vmcnt(2)" ::: "memory");
  __builtin_amdgcn_sched_barrier(0);
  pc0 = __builtin_amdgcn_exp2f(fmaf(lv0[0], L2E, NC));
  pc1 = __builtin_amdgcn_exp2f(fmaf(lv0[1], L2E, NC));
  pc2 = __builtin_amdgcn_exp2f(fmaf(lv0[2], L2E, NC));
  pc3 = __builtin_amdgcn_exp2f(fmaf(lv0[3], L2E, NC));

  float lm = 0.f;

#define SCAN_STEP(T, LVNXT, LVISS, CUR, TAILF)                                    \
  {                                                                               \
    const unsigned* sc = st + (CUR) * 1024;                                       \
    u32x4 b0 = *(const u32x4*)&sc[rd0];                                           \
    u32x4 b1 = *(const u32x4*)&sc[rd1];                                           \
    u32x4 b2 = *(const u32x4*)&sc[rd2];                                           \
    u32x4 b3 = *(const u32x4*)&sc[rd3];                                           \
    { /* issue load for step T+3 into the buffer freed at step T-1 */             \
      int ts = TAILF ? min((T) + 3, L - 1) : ((T) + 3);                           \
      const float* lp = lbase + (size_t)ts * C_;                                  \
      asm volatile("global_load_dwordx4 %0, %1, off" : "=v"(LVISS) : "v"(lp));    \
    }                                                                             \
    asm volatile("s_waitcnt vmcnt(2)" ::: "memory");  /* LV[T+1] resident */      \
    __builtin_amdgcn_sched_barrier(0);                                            \
    /* p for step T+1 — runs under the MFMA/lgkm shadow, off the chain */         \
    float pn0 = __builtin_amdgcn_exp2f(fmaf(LVNXT[0], L2E, NC));                  \
    float pn1 = __builtin_amdgcn_exp2f(fmaf(LVNXT[1], L2E, NC));                  \
    float pn2 = __builtin_amdgcn_exp2f(fmaf(LVNXT[2], L2E, NC));                  \
    float pn3 = __builtin_amdgcn_exp2f(fmaf(LVNXT[3], L2E, NC));                  \
    f32x4 z = {0.f, 0.f, 0.f, 0.f};                                               \
    f32x4 a0 = __builtin_amdgcn_mfma_f32_16x16x32_bf16(af[0], __builtin_bit_cast(short8, b0), z, 0, 0, 0); \
    f32x4 a1 = __builtin_amdgcn_mfma_f32_16x16x32_bf16(af[1], __builtin_bit_cast(short8, b1), z, 0, 0, 0); \
    f32x4 a2 = __builtin_amdgcn_mfma_f32_16x16x32_bf16(af[2], __builtin_bit_cast(short8, b2), z, 0, 0, 0); \
    f32x4 a3 = __builtin_amdgcn_mfma_f32_16x16x32_bf16(af[3], __builtin_bit_cast(short8, b3), z, 0, 0, 0); \
    float wv0 = ((a0[0] + a1[0]) + (a2[0] + a3[0])) * pc0;                        \
    float wv1 = ((a0[1] + a1[1]) + (a2[1] + a3[1])) * pc1;                        \
    float wv2 = ((a0[2] + a1[2]) + (a2[2] + a3[2])) * pc2;                        \
    float wv3 = ((a0[3] + a1[3]) + (a2[3] + a3[3])) * pc3;                        \
    if (((T) & 7) == 7) {                                                         \
      float tm = fmaxf(fmaxf(wv0, wv1), fmaxf(wv2, wv3));                         \
      tm = fmaxf(tm, __shfl_xor(tm, 16));                                         \
      tm = fmaxf(tm, __shfl_xor(tm, 32));                                         \
      if (lg == 0) mred[lj][w] = tm;                                              \
      bar();                                                                      \
      f32x4 ma = *(const f32x4*)&mred[lj][0];                                     \
      f32x4 mb = *(const f32x4*)&mred[lj][4];                                     \
      float m = fmaxf(fmaxf(fmaxf(ma[0], ma[1]), fmaxf(ma[2], ma[3])),            \
                      fmaxf(fmaxf(mb[0], mb[1]), fmaxf(mb[2], mb[3])));           \
      float rm = __builtin_amdgcn_rcpf(m);                                        \
      wv0 *= rm; wv1 *= rm; wv2 *= rm; wv3 *= rm;                                 \
      if (!(TAILF) || (T) < len_n) lm += LN2 * __builtin_amdgcn_logf(m);          \
    }                                                                             \
    unsigned pk0 = cvtpk(wv0, wv1);                                               \
    unsigned pk1 = cvtpk(wv2, wv3);                                               \
    if (TAILF) {                                                                  \
      bool alive = (T) < len_n;                                                   \
      pk0 = alive ? pk0 : prev0;                                                  \
      pk1 = alive ? pk1 : prev1;                                                  \
    }                                                                             \
    *(unsigned long long*)&st[((CUR) ^ 1) * 1024 + wr_off] =                      \
        ((unsigned long long)pk1 << 32) | pk0;                                    \
    prev0 = pk0; prev1 = pk1;                                                     \
    pc0 = pn0; pc1 = pn1; pc2 = pn2; pc3 = pn3;                                   \
    bar();                                                                        \
  }

  for (int t = 0; t < T_main; t += 4) {
    SCAN_STEP(t,     lv1, lv3, 0, false);
    SCAN_STEP(t + 1, lv2, lv0, 1, false);
    SCAN_STEP(t + 2, lv3, lv1, 0, false);
    SCAN_STEP(t + 3, lv0, lv2, 1, false);
  }
  for (int t = T_main; t < L; t += 4) {
    SCAN_STEP(t,     lv1, lv3, 0, true);
    SCAN_STEP(t + 1, lv2, lv0, 1, true);
    SCAN_STEP(t + 2, lv3, lv1, 0, true);
    SCAN_STEP(t + 3, lv0, lv2, 1, true);
  }
#undef SCAN_STEP

  // ---- epilogue: out[n] = 8*len + lm + ln(sum_j A_j * exp(T[end,j])) - sent ----
  {
    const float* te = trans + (size_t)end_tag * C_ + j0;
    float es = bf2f((unsigned short)(prev0 & 0xffff)) * expf(te[0])
             + bf2f((unsigned short)(prev0 >> 16))    * expf(te[1])
             + bf2f((unsigned short)(prev1 & 0xffff)) * expf(te[2])
             + bf2f((unsigned short)(prev1 >> 16))    * expf(te[3]);
    es += __shfl_xor(es, 16);
    es += __shfl_xor(es, 32);
    if (lg == 0) mred[lj][w] = es;
    bar();
    if (w == 0 && lg == 0) {
      f32x4 a = *(const f32x4*)&mred[lj][0];
      f32x4 b = *(const f32x4*)&mred[lj][4];
      float S = ((a[0] + a[1]) + (a[2] + a[3])) + ((b[0] + b[1]) + (b[2] + b[3]));
      float total = 8.0f * (float)len_n + lm + LN2 * __builtin_amdgcn_logf(S);
      out[n0 + lj] = total - sent_lds[lj];
    }
  }
}

extern "C" void kernel_launch(void* const* d_in, const int* in_sizes, int n_in,
                              void* d_out, int out_size, void* d_ws, size_t ws_size,
                              hipStream_t stream) {
  const float* logits = (const float*)d_in[0];
  const float* trans  = (const float*)d_in[1];
  const int*   labels = (const int*)d_in[2];
  const void*  mask   = (const void*)d_in[3];
  const int* startp = (const int*)d_in[4];
  const int* endp   = (const int*)d_in[5];
  float* out  = (float*)d_out;

  const int N = out_size;            // 512
  const int L = in_sizes[2] / N;     // 1024

  crf_scan<<<N / 16, 512, 0, stream>>>(logits, trans, labels, mask, out, L, startp, endp);
}

// Round 17
// 347.559 us; speedup vs baseline: 1.1457x; 1.1457x over previous
//
#include <hip/hip_runtime.h>
#include <stdint.h>

#define C_ 128

typedef __attribute__((ext_vector_type(8))) short short8;
typedef __attribute__((ext_vector_type(4))) float f32x4;
typedef __attribute__((ext_vector_type(4))) unsigned int u32x4;

__device__ __forceinline__ unsigned short f2bf(float x){
  unsigned u = __builtin_bit_cast(unsigned, x);
  return (unsigned short)((u + 0x7FFFu + ((u >> 16) & 1u)) >> 16);
}
__device__ __forceinline__ float bf2f(unsigned short h){
  unsigned u = ((unsigned)h) << 16;
  return __builtin_bit_cast(float, u);
}
__device__ __forceinline__ unsigned cvtpk(float lo, float hi){
  unsigned r;
  asm("v_cvt_pk_bf16_f32 %0, %1, %2" : "=v"(r) : "v"(lo), "v"(hi));
  return r;
}
__device__ __forceinline__ void bar(){
  asm volatile("s_waitcnt lgkmcnt(0)" ::: "memory");
  __builtin_amdgcn_s_barrier();
  asm volatile("" ::: "memory");
}

// mask dtype probe: lengths >= L/2 >= 4, so first 4 mask elems are true.
__device__ __forceinline__ bool mask_is_i32(const void* mask){
  return ((const unsigned*)mask)[0] == 1u;
}

// ---------------- fused launch: blocks 0..31 scan, blocks 32..63 path-score ----------
// Scan = r15 verbatim (green, 350us): 8-wave j-split, distance-3 prefetch + off-chain
// p-precompute, 4 independent MFMA accumulators, eager renorm every 8 (lazy renorm
// blacklisted at 8 waves: r10/r11 NaN). Path-score runs CONCURRENTLY on blocks 32..63
// (the CUs the scan leaves idle); handoff via d_ws + per-pair release/acquire flag.
// All 64 blocks are co-resident (<=256 CUs), so the consumer's spin terminates.
__global__ __launch_bounds__(512, 1) void crf_fused(
    const float* __restrict__ logits,
    const float* __restrict__ trans,
    const int*   __restrict__ labels,
    const void*  __restrict__ mask,
    float* __restrict__ ws_sent,     // [512] sent scores
    int*   __restrict__ flags,       // [32] per-pair ready flags (zeroed per call)
    float* __restrict__ out,
    int L,
    const int* __restrict__ startp, const int* __restrict__ endp)
{
  const int bid = blockIdx.x;
  const int tid = threadIdx.x;
  const int start_tag = *startp;
  const int end_tag   = *endp;
  const bool i32m = mask_is_i32(mask);
  const float LN2 = 0.69314718055994530942f;

  if (bid >= 32) {
    // ---------------- producer: path scores for samples [(bid-32)*16, +16) ----------
    const int pb = bid - 32;
    const int n0 = pb * 16;
    const int s  = tid >> 5;       // sample 0..15
    const int g  = tid & 31;       // lane within sample-group
    const int*  lab  = labels + (size_t)(n0 + s) * L;
    const float* lrow = logits + (size_t)(n0 + s) * L * C_;
    const int*           m32 = (const int*)mask + (size_t)(n0 + s) * L;
    const unsigned char* m8  = (const unsigned char*)mask + (size_t)(n0 + s) * L;
    float acc = 0.f;
    for (int t = g; t < L; t += 32) {
      int mt = i32m ? m32[t] : (int)m8[t];
      if (mt) {
        int lt  = lab[t];
        int mnx = (t + 1 < L) ? (i32m ? m32[t + 1] : (int)m8[t + 1]) : 0;
        int nxt = mnx ? lab[t + 1] : end_tag;
        acc += lrow[(size_t)t * C_ + lt] + trans[(size_t)nxt * C_ + lt];
      }
    }
    #pragma unroll
    for (int m = 1; m < 32; m <<= 1) acc += __shfl_xor(acc, m);
    if (g == 0) ws_sent[n0 + s] = acc + trans[(size_t)lab[0] * C_ + start_tag];
    __syncthreads();
    if (tid == 0) {
      __threadfence();   // device-scope: sent values visible before flag
      __hip_atomic_store(&flags[pb], 1, __ATOMIC_RELEASE, __HIP_MEMORY_SCOPE_AGENT);
    }
    return;
  }

  // ---------------- consumer: the r15 scan, samples [bid*16, +16) ----------------
  __shared__ unsigned st[2 * 1024];   // 8 KB state, double-buffered, chunk-swizzled
  __shared__ float mred[16][8];

  const int w   = tid >> 6;     // wave 0..7: owns tags [16w,16w+16)
  const int l   = tid & 63;
  const int lj  = l & 15;       // sample within block
  const int lg  = l >> 4;       // 0..3
  const int j0  = 16 * w + 4 * lg;
  const int n0  = bid * 16;

  // ---- length of sample lj (each wave redundantly) ----
  int cnt = 0;
  {
    const int seg = L >> 2;
    if (i32m) {
      const int4* m4 = (const int4*)((const int*)mask + (size_t)(n0 + lj) * L + lg * seg);
      for (int i = 0; i < (seg >> 2); i++) {
        int4 v = m4[i];
        cnt += (v.x != 0) + (v.y != 0) + (v.z != 0) + (v.w != 0);
      }
    } else {
      const unsigned* mr = (const unsigned*)((const unsigned char*)mask + (size_t)(n0 + lj) * L + lg * seg);
      for (int i = 0; i < (seg >> 2); i++) cnt += __popc(mr[i]);
    }
    cnt += __shfl_xor(cnt, 16);
    cnt += __shfl_xor(cnt, 32);
  }
  const int len_n = cnt;
  int mn = len_n;
  mn = min(mn, __shfl_xor(mn, 1));
  mn = min(mn, __shfl_xor(mn, 2));
  mn = min(mn, __shfl_xor(mn, 4));
  mn = min(mn, __shfl_xor(mn, 8));
  const int T_main = (mn - 3) & ~3;   // multiple of 4; main loop fully alive

  // ---- A-frags: E^T rows [16w,16w+16), natural k-map k=32ks+8lg+e ----
  short8 af[4];
  #pragma unroll
  for (int ks = 0; ks < 4; ks++) {
    const float* tp = trans + (size_t)(16 * w + lj) * C_ + 32 * ks + 8 * lg;
    f32x4 e0 = *(const f32x4*)tp;
    f32x4 e1 = *(const f32x4*)(tp + 4);
    short8 f;
    #pragma unroll
    for (int i = 0; i < 4; i++) f[i] = (short)f2bf(expf(e0[i]));
    #pragma unroll
    for (int i = 0; i < 4; i++) f[4 + i] = (short)f2bf(expf(e1[i]));
    af[ks] = f;
  }

  // ---- init state: zeros + 1.0 at start_tag, in st[0] ----
  ((u32x4*)st)[tid] = (u32x4){0, 0, 0, 0};
  bar();
  if (tid < 16) {
    int phys = ((start_tag >> 3) ^ tid) & 15;
    st[tid * 64 + phys * 4 + ((start_tag & 7) >> 1)] =
        (start_tag & 1) ? 0x3F800000u : 0x00003F80u;
  }
  bar();

  unsigned prev0 = 0, prev1 = 0;
  #pragma unroll
  for (int i = 0; i < 4; i++)
    if (j0 + i == start_tag) {
      if (i == 0) prev0 |= 0x3F80u;
      if (i == 1) prev0 |= 0x3F80u << 16;
      if (i == 2) prev1 |= 0x3F80u;
      if (i == 3) prev1 |= 0x3F80u << 16;
    }

  // ---- LDS word offsets (u32 units), 16B-chunk XOR swizzle: phys = logical ^ lj ----
  const int wr_off = lj * 64 + ((((2 * w + (lg >> 1)) ^ lj) & 15) << 2) + ((lg & 1) << 1);
  const int rd0 = lj * 64 + ((((0 + lg) ^ lj) & 15) << 2);
  const int rd1 = lj * 64 + ((((4 + lg) ^ lj) & 15) << 2);
  const int rd2 = lj * 64 + ((((8 + lg) ^ lj) & 15) << 2);
  const int rd3 = lj * 64 + ((((12 + lg) ^ lj) & 15) << 2);

  const float L2E = 1.44269504088896340736f;
  const float NC  = -8.0f * L2E;

  // ---- logits: lane loads its own 4 tags; 4 rotating buffers (distance-3) ----
  const float* lbase = logits + (size_t)(n0 + lj) * L * C_ + j0;
  f32x4 lv0, lv1, lv2, lv3;
  asm volatile("global_load_dwordx4 %0, %1, off" : "=v"(lv0) : "v"(lbase));
  asm volatile("global_load_dwordx4 %0, %1, off" : "=v"(lv1) : "v"(lbase + C_));
  asm volatile("global_load_dwordx4 %0, %1, off" : "=v"(lv2) : "v"(lbase + 2 * C_));

  // prologue: p for step 0 (vmcnt(2): lv0 arrived, lv1/lv2 still in flight)
  float pc0, pc1, pc2, pc3;
  asm volatile("s_waitcnt vmcnt(2)" ::: "memory");
  __builtin_amdgcn_sched_barrier(0);
  pc0 = __builtin_amdgcn_exp2f(fmaf(lv0[0], L2E, NC));
  pc1 = __builtin_amdgcn_exp2f(fmaf(lv0[1], L2E, NC));
  pc2 = __builtin_amdgcn_exp2f(fmaf(lv0[2], L2E, NC));
  pc3 = __builtin_amdgcn_exp2f(fmaf(lv0[3], L2E, NC));

  float lm = 0.f;

#define SCAN_STEP(T, LVNXT, LVISS, CUR, TAILF)                                    \
  {                                                                               \
    const unsigned* sc = st + (CUR) * 1024;                                       \
    u32x4 b0 = *(const u32x4*)&sc[rd0];                                           \
    u32x4 b1 = *(const u32x4*)&sc[rd1];                                           \
    u32x4 b2 = *(const u32x4*)&sc[rd2];                                           \
    u32x4 b3 = *(const u32x4*)&sc[rd3];                                           \
    { /* issue load for step T+3 into the buffer freed at step T-1 */             \
      int ts = TAILF ? min((T) + 3, L - 1) : ((T) + 3);                           \
      const float* lp = lbase + (size_t)ts * C_;                                  \
      asm volatile("global_load_dwordx4 %0, %1, off" : "=v"(LVISS) : "v"(lp));    \
    }                                                                             \
    asm volatile("s_waitcnt vmcnt(2)" ::: "memory");  /* LV[T+1] resident */      \
    __builtin_amdgcn_sched_barrier(0);                                            \
    /* p for step T+1 — runs under the MFMA/lgkm shadow, off the chain */         \
    float pn0 = __builtin_amdgcn_exp2f(fmaf(LVNXT[0], L2E, NC));                  \
    float pn1 = __builtin_amdgcn_exp2f(fmaf(LVNXT[1], L2E, NC));                  \
    float pn2 = __builtin_amdgcn_exp2f(fmaf(LVNXT[2], L2E, NC));                  \
    float pn3 = __builtin_amdgcn_exp2f(fmaf(LVNXT[3], L2E, NC));                  \
    f32x4 z = {0.f, 0.f, 0.f, 0.f};                                               \
    f32x4 a0 = __builtin_amdgcn_mfma_f32_16x16x32_bf16(af[0], __builtin_bit_cast(short8, b0), z, 0, 0, 0); \
    f32x4 a1 = __builtin_amdgcn_mfma_f32_16x16x32_bf16(af[1], __builtin_bit_cast(short8, b1), z, 0, 0, 0); \
    f32x4 a2 = __builtin_amdgcn_mfma_f32_16x16x32_bf16(af[2], __builtin_bit_cast(short8, b2), z, 0, 0, 0); \
    f32x4 a3 = __builtin_amdgcn_mfma_f32_16x16x32_bf16(af[3], __builtin_bit_cast(short8, b3), z, 0, 0, 0); \
    float wv0 = ((a0[0] + a1[0]) + (a2[0] + a3[0])) * pc0;                        \
    float wv1 = ((a0[1] + a1[1]) + (a2[1] + a3[1])) * pc1;                        \
    float wv2 = ((a0[2] + a1[2]) + (a2[2] + a3[2])) * pc2;                        \
    float wv3 = ((a0[3] + a1[3]) + (a2[3] + a3[3])) * pc3;                        \
    if (((T) & 7) == 7) {                                                         \
      float tm = fmaxf(fmaxf(wv0, wv1), fmaxf(wv2, wv3));                         \
      tm = fmaxf(tm, __shfl_xor(tm, 16));                                         \
      tm = fmaxf(tm, __shfl_xor(tm, 32));                                         \
      if (lg == 0) mred[lj][w] = tm;                                              \
      bar();                                                                      \
      f32x4 ma = *(const f32x4*)&mred[lj][0];                                     \
      f32x4 mb = *(const f32x4*)&mred[lj][4];                                     \
      float m = fmaxf(fmaxf(fmaxf(ma[0], ma[1]), fmaxf(ma[2], ma[3])),            \
                      fmaxf(fmaxf(mb[0], mb[1]), fmaxf(mb[2], mb[3])));           \
      float rm = __builtin_amdgcn_rcpf(m);                                        \
      wv0 *= rm; wv1 *= rm; wv2 *= rm; wv3 *= rm;                                 \
      if (!(TAILF) || (T) < len_n) lm += LN2 * __builtin_amdgcn_logf(m);          \
    }                                                                             \
    unsigned pk0 = cvtpk(wv0, wv1);                                               \
    unsigned pk1 = cvtpk(wv2, wv3);                                               \
    if (TAILF) {                                                                  \
      bool alive = (T) < len_n;                                                   \
      pk0 = alive ? pk0 : prev0;                                                  \
      pk1 = alive ? pk1 : prev1;                                                  \
    }                                                                             \
    *(unsigned long long*)&st[((CUR) ^ 1) * 1024 + wr_off] =                      \
        ((unsigned long long)pk1 << 32) | pk0;                                    \
    prev0 = pk0; prev1 = pk1;                                                     \
    pc0 = pn0; pc1 = pn1; pc2 = pn2; pc3 = pn3;                                   \
    bar();                                                                        \
  }

  for (int t = 0; t < T_main; t += 4) {
    SCAN_STEP(t,     lv1, lv3, 0, false);
    SCAN_STEP(t + 1, lv2, lv0, 1, false);
    SCAN_STEP(t + 2, lv3, lv1, 0, false);
    SCAN_STEP(t + 3, lv0, lv2, 1, false);
  }
  for (int t = T_main; t < L; t += 4) {
    SCAN_STEP(t,     lv1, lv3, 0, true);
    SCAN_STEP(t + 1, lv2, lv0, 1, true);
    SCAN_STEP(t + 2, lv3, lv1, 0, true);
    SCAN_STEP(t + 3, lv0, lv2, 1, true);
  }
#undef SCAN_STEP

  // ---- epilogue: out[n] = 8*len + lm + ln(sum_j A_j * exp(T[end,j])) - sent ----
  {
    const float* te = trans + (size_t)end_tag * C_ + j0;
    float es = bf2f((unsigned short)(prev0 & 0xffff)) * expf(te[0])
             + bf2f((unsigned short)(prev0 >> 16))    * expf(te[1])
             + bf2f((unsigned short)(prev1 & 0xffff)) * expf(te[2])
             + bf2f((unsigned short)(prev1 >> 16))    * expf(te[3]);
    es += __shfl_xor(es, 16);
    es += __shfl_xor(es, 32);
    if (lg == 0) mred[lj][w] = es;
    bar();
    if (w == 0 && lg == 0) {
      // wait for the partner producer block (co-resident; ~300us slack vs ~30us work)
      while (__hip_atomic_load(&flags[bid], __ATOMIC_ACQUIRE,
                               __HIP_MEMORY_SCOPE_AGENT) == 0)
        __builtin_amdgcn_s_sleep(8);
      f32x4 a = *(const f32x4*)&mred[lj][0];
      f32x4 b = *(const f32x4*)&mred[lj][4];
      float S = ((a[0] + a[1]) + (a[2] + a[3])) + ((b[0] + b[1]) + (b[2] + b[3]));
      float total = 8.0f * (float)len_n + lm + LN2 * __builtin_amdgcn_logf(S);
      out[n0 + lj] = total - ws_sent[n0 + lj];
    }
  }
}

extern "C" void kernel_launch(void* const* d_in, const int* in_sizes, int n_in,
                              void* d_out, int out_size, void* d_ws, size_t ws_size,
                              hipStream_t stream) {
  const float* logits = (const float*)d_in[0];
  const float* trans  = (const float*)d_in[1];
  const int*   labels = (const int*)d_in[2];
  const void*  mask   = (const void*)d_in[3];
  const int* startp = (const int*)d_in[4];
  const int* endp   = (const int*)d_in[5];
  float* out  = (float*)d_out;

  const int N = out_size;            // 512
  const int L = in_sizes[2] / N;     // 1024

  float* ws_sent = (float*)d_ws;                       // 512 floats
  int*   flags   = (int*)((char*)d_ws + 2048);         // 32 ints

  hipMemsetAsync(flags, 0, 32 * sizeof(int), stream);  // reset flags each call
  crf_fused<<<64, 512, 0, stream>>>(logits, trans, labels, mask,
                                    ws_sent, flags, out, L, startp, endp);
}